// Round 8
// baseline (198.551 us; speedup 1.0000x reference)
//
#include <hip/hip_runtime.h>

typedef __attribute__((ext_vector_type(4))) float f32x4;
typedef __attribute__((ext_vector_type(8))) __bf16 bf16x8;
typedef __attribute__((ext_vector_type(4))) __bf16 bf16x4;

#define DEV __device__ __forceinline__

DEV f32x4 mfma_bf16(bf16x8 a, bf16x8 b, f32x4 c) {
  return __builtin_amdgcn_mfma_f32_16x16x32_bf16(a, b, c, 0, 0, 0);
}

DEV void glds16(const void* gp, void* lp) {
  __builtin_amdgcn_global_load_lds((const __attribute__((address_space(1))) void*)gp,
                                   (__attribute__((address_space(3))) void*)lp, 16, 0, 0);
}

DEV float fast_exp2(float x) {
#if __has_builtin(__builtin_amdgcn_exp2f)
  return __builtin_amdgcn_exp2f(x);
#else
  float r;
  asm("v_exp_f32 %0, %1" : "=v"(r) : "v"(x));
  return r;
#endif
}

// Pipeline protocol (r5/r6 post-mortem, rule-18 race closed):
//   stage(next); vmcnt(4); SB0; s_barrier; SB0;  [ds_read+MFMA]
//   lgkmcnt(0); SB0; s_barrier; SB0
// The unconditional lgkmcnt(0)+sched_barrier before the end barrier guarantees
// no ds_read of buf[cur] is outstanding when any wave starts staging into it.
#define SB0() __builtin_amdgcn_sched_barrier(0)

// ---------------- f32 -> bf16 conversion (with zero padding past n_in) ----------------
__global__ __launch_bounds__(256) void cvt_bf16(const float* __restrict__ in,
                                                __bf16* __restrict__ out, int n_in) {
  long long i = (long long)blockIdx.x * 256 + threadIdx.x;
  long long e = i * 8;
  bf16x8 o = {};
  if (e < n_in) {
    const f32x4* ip = (const f32x4*)(in + e);
    f32x4 a = ip[0], b = ip[1];
#pragma unroll
    for (int j = 0; j < 4; ++j) { o[j] = (__bf16)a[j]; o[j + 4] = (__bf16)b[j]; }
  }
  *(bf16x8*)(out + e) = o;
}

// fused 4-weight convert: 800 blocks each, 1280*1280 elements exact
__global__ __launch_bounds__(256) void cvt_w4(const float* __restrict__ a, const float* __restrict__ b,
                                              const float* __restrict__ c, const float* __restrict__ d,
                                              __bf16* __restrict__ oa, __bf16* __restrict__ ob,
                                              __bf16* __restrict__ oc, __bf16* __restrict__ od) {
  int blk = blockIdx.x;
  int which = blk / 800;
  int bb = blk - which * 800;
  const float* in = which == 0 ? a : which == 1 ? b : which == 2 ? c : d;
  __bf16* out = which == 0 ? oa : which == 1 ? ob : which == 2 ? oc : od;
  long long e = ((long long)bb * 256 + threadIdx.x) * 8;
  const f32x4* ip = (const f32x4*)(in + e);
  f32x4 x = ip[0], y = ip[1];
  bf16x8 o;
#pragma unroll
  for (int j = 0; j < 4; ++j) { o[j] = (__bf16)x[j]; o[j + 4] = (__bf16)y[j]; }
  *(bf16x8*)(out + e) = o;
}

// LDS chunk-swizzle (T2, both-sides per rule 21):
//  LDS tile [128 rows][4 chunks of 8 bf16]; LDS(row, c) holds global chunk
//  c ^ ((row>>1)&3). Staged via pre-swizzled global source col-group
//  cg = 8*((tid&3) ^ ((tid>>3)&3)); read chunk = g ^ ((lane>>1)&3).
//  Read banks: 16(r&1) + 4(g^((r>>1)&3)) -> 8 bank-groups x 2 lanes (conflict-free).

// ---------------- merged QKV GEMM: X[6144][1280] @ Wqkv[3840][1280]^T ----------------
// counted-vmcnt double buffer + LDS swizzle + 2D XCD tiling.
// n-panel 0..9 -> Q (bias, SQ), 10..19 -> K, 20..29 -> V (bias, V^T packed store).
__global__ __launch_bounds__(256) void gemm_qkv(const __bf16* __restrict__ A,
                                                const __bf16* __restrict__ Bw,
                                                const float* __restrict__ qbias,
                                                const float* __restrict__ vbias,
                                                __bf16* __restrict__ Qo,
                                                __bf16* __restrict__ Ko,
                                                __bf16* __restrict__ Vto,
                                                float sq) {
  __shared__ __align__(16) __bf16 lds[2 * 8192];  // per buf: A[128][32] at +0, B at +4096
  const int tid = threadIdx.x;
  const int lane = tid & 63, wave = tid >> 6;
  // 2D XCD tiling: xcd grid 4(m-groups of 12) x 2(n-groups of 15); n-major within XCD
  const int orig = blockIdx.x;
  const int xcd = orig & 7, i = orig >> 3;          // i in [0,180)
  const int m_idx = (xcd & 3) * 12 + i % 12;        // [0,48)
  const int n_idx = (xcd >> 2) * 15 + i / 12;       // [0,30)
  const int m0 = m_idx * 128, n0 = n_idx * 128;
  const int wm = (wave >> 1) * 64, wn = (wave & 1) * 64;
  const int r = lane & 15, g = lane >> 4;

  const f32x4 fz = {0.f, 0.f, 0.f, 0.f};
  f32x4 acc[4][4];
#pragma unroll
  for (int mi = 0; mi < 4; ++mi)
#pragma unroll
    for (int ni = 0; ni < 4; ++ni) acc[mi][ni] = fz;

  const int cg = 8 * ((tid & 3) ^ ((tid >> 3) & 3));  // pre-swizzled source chunk
  const __bf16* Abase = A + (size_t)(m0 + (tid >> 2)) * 1280 + cg;
  const __bf16* Bbase = Bw + (size_t)(n0 + (tid >> 2)) * 1280 + cg;
  const int wA = wave * 512;
  const int csw = (g ^ ((lane >> 1) & 3)) * 8;        // swizzled read chunk offset

  auto stage = [&](int buf, int kt2) {
    const int k0 = kt2 * 32;
    __bf16* L = &lds[buf * 8192];
    glds16(Abase + k0, L + wA);
    glds16(Abase + 64 * 1280 + k0, L + wA + 2048);
    glds16(Bbase + k0, L + 4096 + wA);
    glds16(Bbase + 64 * 1280 + k0, L + 6144 + wA);
  };

  stage(0, 0);
  for (int kt = 0; kt < 40; ++kt) {
    const int cur = kt & 1;
    if (kt + 1 < 40) {
      stage(cur ^ 1, kt + 1);
      asm volatile("s_waitcnt vmcnt(4)" ::: "memory");  // cur tile landed; next in flight
    } else {
      asm volatile("s_waitcnt vmcnt(0)" ::: "memory");
    }
    SB0();
    __builtin_amdgcn_s_barrier();
    SB0();

    const __bf16* Ab = &lds[cur * 8192];
    const __bf16* Bb = Ab + 4096;
    bf16x8 af[4], bfr[4];
#pragma unroll
    for (int mi = 0; mi < 4; ++mi)
      af[mi] = *(const bf16x8*)&Ab[(wm + mi * 16 + r) * 32 + csw];
#pragma unroll
    for (int ni = 0; ni < 4; ++ni)
      bfr[ni] = *(const bf16x8*)&Bb[(wn + ni * 16 + r) * 32 + csw];
#pragma unroll
    for (int mi = 0; mi < 4; ++mi)
#pragma unroll
      for (int ni = 0; ni < 4; ++ni)
        acc[mi][ni] = mfma_bf16(af[mi], bfr[ni], acc[mi][ni]);

    asm volatile("s_waitcnt lgkmcnt(0)" ::: "memory");  // all my ds_reads retired
    SB0();
    __builtin_amdgcn_s_barrier();
    SB0();
  }

  const int which = n_idx / 10;                    // 0=Q 1=K 2=V (block-uniform)
  const int colP = n0 - which * 1280 + wn;         // panel-local col base
  const float scale = (which == 0) ? sq : 1.f;

#pragma unroll
  for (int ni = 0; ni < 4; ++ni) {
    const int col = colP + ni * 16 + r;
    const float bv = (which == 0) ? qbias[col] : (which == 2) ? vbias[col] : 0.f;
#pragma unroll
    for (int mi = 0; mi < 4; ++mi) {
      if (which == 2) {
        const int row0 = m0 + wm + mi * 16 + g * 4;
        if (row0 < 6000) {
          const int bidx = row0 / 1500;            // 4-row group never straddles
          const int t = row0 - bidx * 1500;
          union { __bf16 h[4]; unsigned long long u; } pk;
#pragma unroll
          for (int rr = 0; rr < 4; ++rr) pk.h[rr] = (__bf16)(acc[mi][ni][rr] + bv);
          *(unsigned long long*)&Vto[((size_t)(bidx * 1280 + col)) * 1536 + t] = pk.u;
        }
      } else {
        __bf16* dst = (which == 0) ? Qo : Ko;
#pragma unroll
        for (int rr = 0; rr < 4; ++rr) {
          const int row = m0 + wm + mi * 16 + g * 4 + rr;
          dst[(size_t)row * 1280 + col] = (__bf16)((acc[mi][ni][rr] + bv) * scale);
        }
      }
    }
  }
}

// ---------------- O-projection GEMM: A[6144][1280] @ W[1280][1280]^T -> f32 ----------
__global__ __launch_bounds__(256) void gemm_o(const __bf16* __restrict__ A,
                                              const __bf16* __restrict__ Bw,
                                              const float* __restrict__ bias,
                                              float* __restrict__ out) {
  __shared__ __align__(16) __bf16 lds[2 * 8192];
  const int tid = threadIdx.x;
  const int lane = tid & 63, wave = tid >> 6;
  // 2D XCD tiling: 480 = 8 * 60; per XCD 12 m-tiles x 5 n-panels, n-major
  const int orig = blockIdx.x;
  const int xcd = orig & 7, i = orig >> 3;          // i in [0,60)
  const int m_idx = (xcd & 3) * 12 + i % 12;        // [0,48)
  const int n_idx = (xcd >> 2) * 5 + i / 12;        // [0,10)
  const int m0 = m_idx * 128, n0 = n_idx * 128;
  const int wm = (wave >> 1) * 64, wn = (wave & 1) * 64;
  const int r = lane & 15, g = lane >> 4;

  const f32x4 fz = {0.f, 0.f, 0.f, 0.f};
  f32x4 acc[4][4];
#pragma unroll
  for (int mi = 0; mi < 4; ++mi)
#pragma unroll
    for (int ni = 0; ni < 4; ++ni) acc[mi][ni] = fz;

  const int cg = 8 * ((tid & 3) ^ ((tid >> 3) & 3));
  const __bf16* Abase = A + (size_t)(m0 + (tid >> 2)) * 1280 + cg;
  const __bf16* Bbase = Bw + (size_t)(n0 + (tid >> 2)) * 1280 + cg;
  const int wA = wave * 512;
  const int csw = (g ^ ((lane >> 1) & 3)) * 8;

  auto stage = [&](int buf, int kt2) {
    const int k0 = kt2 * 32;
    __bf16* L = &lds[buf * 8192];
    glds16(Abase + k0, L + wA);
    glds16(Abase + 64 * 1280 + k0, L + wA + 2048);
    glds16(Bbase + k0, L + 4096 + wA);
    glds16(Bbase + 64 * 1280 + k0, L + 6144 + wA);
  };

  stage(0, 0);
  for (int kt = 0; kt < 40; ++kt) {
    const int cur = kt & 1;
    if (kt + 1 < 40) {
      stage(cur ^ 1, kt + 1);
      asm volatile("s_waitcnt vmcnt(4)" ::: "memory");
    } else {
      asm volatile("s_waitcnt vmcnt(0)" ::: "memory");
    }
    SB0();
    __builtin_amdgcn_s_barrier();
    SB0();

    const __bf16* Ab = &lds[cur * 8192];
    const __bf16* Bb = Ab + 4096;
    bf16x8 af[4], bfr[4];
#pragma unroll
    for (int mi = 0; mi < 4; ++mi)
      af[mi] = *(const bf16x8*)&Ab[(wm + mi * 16 + r) * 32 + csw];
#pragma unroll
    for (int ni = 0; ni < 4; ++ni)
      bfr[ni] = *(const bf16x8*)&Bb[(wn + ni * 16 + r) * 32 + csw];
#pragma unroll
    for (int mi = 0; mi < 4; ++mi)
#pragma unroll
      for (int ni = 0; ni < 4; ++ni)
        acc[mi][ni] = mfma_bf16(af[mi], bfr[ni], acc[mi][ni]);

    asm volatile("s_waitcnt lgkmcnt(0)" ::: "memory");
    SB0();
    __builtin_amdgcn_s_barrier();
    SB0();
  }

#pragma unroll
  for (int ni = 0; ni < 4; ++ni) {
    const int col = n0 + wn + ni * 16 + r;
    const float bv = bias[col];
#pragma unroll
    for (int mi = 0; mi < 4; ++mi) {
#pragma unroll
      for (int rr = 0; rr < 4; ++rr) {
        const int row = m0 + wm + mi * 16 + g * 4 + rr;
        if (row < 6000) out[(size_t)row * 1280 + col] = acc[mi][ni][rr] + bv;
      }
    }
  }
}

// ---------------- flash attention (swapped QK^T, fixed-max softmax, V^T input) -------
// Q pre-scaled by log2(e)/64, so P = exp2(S) directly (scores bounded, no max needed).
// Unchanged from r7 (passing); safe syncthreads pipeline.
__global__ __launch_bounds__(256) void flash_attn(const __bf16* __restrict__ Qg,
                                                  const __bf16* __restrict__ Kg,
                                                  const __bf16* __restrict__ Vt,
                                                  __bf16* __restrict__ Og) {
  constexpr int TQ = 1500, NKT = 24;
  __shared__ __align__(16) __bf16 lds[16384];

  const int tid = threadIdx.x;
  const int lane = tid & 63, w = tid >> 6;
  const int r = lane & 15, g = lane >> 4;

  // T1 XCD swizzle: 960 = 8*120 (bijective); all 12 q-blocks of one (b,h) per XCD
  const int orig = blockIdx.x;
  const int work = (orig & 7) * 120 + (orig >> 3);
  const int bh = work / 12, qb = work - bh * 12;
  const int b = bh / 20, h = bh - b * 20;
  const int q0 = qb * 128;
  const size_t base = (size_t)b * (TQ * 1280) + h * 64;
  const __bf16* Vt_bh = Vt + (size_t)(b * 1280 + h * 64) * 1536;

  // staging coords (dest linear in lane order; sources pre-swizzled)
  const int k_src_col = 8 * ((lane & 7) ^ (lane >> 3));
  const int k_row_loc = w * 8 + (lane >> 3);
  const int v_d_loc = 8 * w + (lane >> 3);
  const int v_chunk = 8 * ((lane & 7) ^ (lane >> 3));

  // Q fragments
  bf16x8 qf[2][2];
#pragma unroll
  for (int qs = 0; qs < 2; ++qs) {
    int t = q0 + w * 32 + qs * 16 + r;
    t = t < TQ ? t : TQ - 1;
    const __bf16* qp = Qg + base + (size_t)t * 1280;
#pragma unroll
    for (int dk = 0; dk < 2; ++dk) qf[qs][dk] = *(const bf16x8*)(qp + dk * 32 + g * 8);
  }

  const f32x4 fz = {0.f, 0.f, 0.f, 0.f};
  f32x4 o_acc[2][4];
#pragma unroll
  for (int qs = 0; qs < 2; ++qs)
#pragma unroll
    for (int ni = 0; ni < 4; ++ni) o_acc[qs][ni] = fz;
  float l_run[2] = {0.f, 0.f};

  auto stage = [&](int buf, int kt2) {
    const int kb = kt2 * 64;
#pragma unroll
    for (int i = 0; i < 2; ++i) {
      int row = kb + i * 32 + k_row_loc;
      row = row < TQ ? row : TQ - 1;
      glds16(Kg + base + (size_t)row * 1280 + k_src_col,
             &lds[buf * 8192 + i * 2048 + w * 512]);
    }
#pragma unroll
    for (int i = 0; i < 2; ++i) {
      glds16(Vt_bh + (size_t)(32 * i + v_d_loc) * 1536 + kb + v_chunk,
             &lds[buf * 8192 + 4096 + i * 2048 + w * 512]);
    }
  };

  stage(0, 0);
  __syncthreads();  // drain prologue prefetch
  for (int kt = 0; kt < NKT; ++kt) {
    const int cur = kt & 1;
    if (kt + 1 < NKT) stage(cur ^ 1, kt + 1);  // prefetch next K/V tile

    const __bf16* Kb = &lds[cur * 8192];

    // ---- S^T = K @ Q^T ----
    f32x4 s[2][4];
#pragma unroll
    for (int qs = 0; qs < 2; ++qs)
#pragma unroll
      for (int nt = 0; nt < 4; ++nt) s[qs][nt] = fz;
#pragma unroll
    for (int dk = 0; dk < 2; ++dk) {
      bf16x8 kf[4];
#pragma unroll
      for (int nt = 0; nt < 4; ++nt) {
        const int row = nt * 16 + r;
        const int sc = (dk * 32 + g * 8) ^ ((r & 7) << 3);
        kf[nt] = *(const bf16x8*)&Kb[row * 64 + sc];
      }
#pragma unroll
      for (int qs = 0; qs < 2; ++qs)
#pragma unroll
        for (int nt = 0; nt < 4; ++nt) s[qs][nt] = mfma_bf16(kf[nt], qf[qs][dk], s[qs][nt]);
    }

    // ---- mask invalid keys (last tile only) ----
    if (kt == NKT - 1) {
#pragma unroll
      for (int nt = 0; nt < 4; ++nt)
#pragma unroll
        for (int rr = 0; rr < 4; ++rr) {
          const int key = kt * 64 + nt * 16 + g * 4 + rr;
          if (key >= TQ) { s[0][nt][rr] = -1.0e30f; s[1][nt][rr] = -1.0e30f; }
        }
    }

    // ---- fixed-max softmax: p = exp2(s); per-lane partial denominator ----
#pragma unroll
    for (int qs = 0; qs < 2; ++qs) {
      float ssum = 0.f;
#pragma unroll
      for (int nt = 0; nt < 4; ++nt)
#pragma unroll
        for (int rr = 0; rr < 4; ++rr) {
          const float p = fast_exp2(s[qs][nt][rr]);
          s[qs][nt][rr] = p;
          ssum += p;
        }
      l_run[qs] += ssum;
    }

    // ---- O^T += V^T @ P^T (key permutation pi applied to BOTH operands) ----
    const __bf16* Vbuf = &lds[cur * 8192 + 4096];
    const int swz = (r & 7) << 3;
#pragma unroll
    for (int ks = 0; ks < 2; ++ks) {
      bf16x8 pa[2];
#pragma unroll
      for (int qs = 0; qs < 2; ++qs) {
        bf16x8 t;
#pragma unroll
        for (int j = 0; j < 4; ++j) {
          t[j] = (__bf16)s[qs][2 * ks][j];
          t[4 + j] = (__bf16)s[qs][2 * ks + 1][j];
        }
        pa[qs] = t;
      }
      const int o1 = (32 * ks + 4 * g) ^ swz;
      const int o2 = (32 * ks + 16 + 4 * g) ^ swz;
#pragma unroll
      for (int ni = 0; ni < 4; ++ni) {
        const int dbase = (16 * ni + r) * 64;
        union { bf16x4 hh[2]; bf16x8 v; } u;
        u.hh[0] = *(const bf16x4*)&Vbuf[dbase + o1];
        u.hh[1] = *(const bf16x4*)&Vbuf[dbase + o2];
#pragma unroll
        for (int qs = 0; qs < 2; ++qs) o_acc[qs][ni] = mfma_bf16(u.v, pa[qs], o_acc[qs][ni]);
      }
    }

    __syncthreads();  // drains prefetch + closes reads of buf[cur]
  }

  // ---- final denominator reduce + normalize + store ----
  float inv[2];
#pragma unroll
  for (int qs = 0; qs < 2; ++qs) {
    float l = l_run[qs];
    l += __shfl_xor(l, 16);
    l += __shfl_xor(l, 32);
    inv[qs] = 1.0f / l;
  }

  __bf16* Ob = &lds[w * 2304];  // 32 rows x 72 stride per wave
#pragma unroll
  for (int qs = 0; qs < 2; ++qs) {
#pragma unroll
    for (int ni = 0; ni < 4; ++ni)
#pragma unroll
      for (int rr = 0; rr < 4; ++rr)
        Ob[(qs * 16 + r) * 72 + ni * 16 + g * 4 + rr] = (__bf16)(o_acc[qs][ni][rr] * inv[qs]);
  }
  __syncthreads();
  const int qg = q0 + w * 32 + (lane >> 1);
  if (qg < TQ) {
#pragma unroll
    for (int v = 0; v < 4; ++v) {
      const int c = (lane & 1) * 32 + v * 8;
      bf16x8 val = *(const bf16x8*)&lds[w * 2304 + (lane >> 1) * 72 + c];
      *(bf16x8*)&Og[base + (size_t)qg * 1280 + c] = val;
    }
  }
}

// ---------------- launcher ----------------
extern "C" void kernel_launch(void* const* d_in, const int* in_sizes, int n_in,
                              void* d_out, int out_size, void* d_ws, size_t ws_size,
                              hipStream_t stream) {
  const float* hs = (const float*)d_in[0];
  const float* qw = (const float*)d_in[1];
  const float* qb = (const float*)d_in[2];
  const float* kw = (const float*)d_in[3];
  const float* vw = (const float*)d_in[4];
  const float* vb = (const float*)d_in[5];
  const float* ow = (const float*)d_in[6];
  const float* ob = (const float*)d_in[7];

  const long long MP = 6144LL * 1280;  // == 5120 * 1536 (Vt reuses this slot)
  const long long WE = 1280LL * 1280;
  __bf16* Xb = (__bf16*)d_ws;
  __bf16* Wq = Xb + MP;   // Wq/Wk/Wv contiguous -> single [3840][1280] B matrix
  __bf16* Wk = Wq + WE;
  __bf16* Wv = Wk + WE;
  __bf16* Wo = Wv + WE;
  __bf16* Qb = Wo + WE;
  __bf16* Kb = Qb + MP;
  __bf16* Vtb = Kb + MP;
  __bf16* Ab = Xb;  // alias: X dead after QKV projection

  cvt_bf16<<<3840, 256, 0, stream>>>(hs, Xb, 7680000);  // pads rows 6000..6143 with 0
  cvt_w4<<<3200, 256, 0, stream>>>(qw, kw, vw, ow, Wq, Wk, Wv, Wo);

  const float SQ = 1.4426950408889634f / 64.f;  // log2(e) / sqrt(64)^2
  gemm_qkv<<<1440, 256, 0, stream>>>(Xb, Wq, qb, vb, Qb, Kb, Vtb, SQ);

  flash_attn<<<960, 256, 0, stream>>>(Qb, Kb, Vtb, Ab);

  gemm_o<<<480, 256, 0, stream>>>(Ab, Wo, ob, (float*)d_out);
}

// Round 9
// 180.154 us; speedup vs baseline: 1.1021x; 1.1021x over previous
//
#include <hip/hip_runtime.h>

typedef __attribute__((ext_vector_type(4))) float f32x4;
typedef __attribute__((ext_vector_type(8))) __bf16 bf16x8;
typedef __attribute__((ext_vector_type(4))) __bf16 bf16x4;

#define DEV __device__ __forceinline__

DEV f32x4 mfma_bf16(bf16x8 a, bf16x8 b, f32x4 c) {
  return __builtin_amdgcn_mfma_f32_16x16x32_bf16(a, b, c, 0, 0, 0);
}

DEV void glds16(const void* gp, void* lp) {
  __builtin_amdgcn_global_load_lds((const __attribute__((address_space(1))) void*)gp,
                                   (__attribute__((address_space(3))) void*)lp, 16, 0, 0);
}

DEV float fast_exp2(float x) {
#if __has_builtin(__builtin_amdgcn_exp2f)
  return __builtin_amdgcn_exp2f(x);
#else
  float r;
  asm("v_exp_f32 %0, %1" : "=v"(r) : "v"(x));
  return r;
#endif
}

#define SB0() __builtin_amdgcn_sched_barrier(0)

// ---------------- f32 -> bf16 conversion (with zero padding past n_in) ----------------
__global__ __launch_bounds__(256) void cvt_bf16(const float* __restrict__ in,
                                                __bf16* __restrict__ out, int n_in) {
  long long i = (long long)blockIdx.x * 256 + threadIdx.x;
  long long e = i * 8;
  bf16x8 o = {};
  if (e < n_in) {
    const f32x4* ip = (const f32x4*)(in + e);
    f32x4 a = ip[0], b = ip[1];
#pragma unroll
    for (int j = 0; j < 4; ++j) { o[j] = (__bf16)a[j]; o[j + 4] = (__bf16)b[j]; }
  }
  *(bf16x8*)(out + e) = o;
}

// fused 4-weight convert: 800 blocks each, 1280*1280 elements exact
__global__ __launch_bounds__(256) void cvt_w4(const float* __restrict__ a, const float* __restrict__ b,
                                              const float* __restrict__ c, const float* __restrict__ d,
                                              __bf16* __restrict__ oa, __bf16* __restrict__ ob,
                                              __bf16* __restrict__ oc, __bf16* __restrict__ od) {
  int blk = blockIdx.x;
  int which = blk / 800;
  int bb = blk - which * 800;
  const float* in = which == 0 ? a : which == 1 ? b : which == 2 ? c : d;
  __bf16* out = which == 0 ? oa : which == 1 ? ob : which == 2 ? oc : od;
  long long e = ((long long)bb * 256 + threadIdx.x) * 8;
  const f32x4* ip = (const f32x4*)(in + e);
  f32x4 x = ip[0], y = ip[1];
  bf16x8 o;
#pragma unroll
  for (int j = 0; j < 4; ++j) { o[j] = (__bf16)x[j]; o[j + 4] = (__bf16)y[j]; }
  *(bf16x8*)(out + e) = o;
}

// ---------------- merged QKV GEMM, fine-interleaved counted schedule ----------------
// X[6144][1280] @ Wqkv[3840][1280]^T. BM=128, BN=256, BK=64, 512 thr = 8 waves (2m x 4n),
// wave output 64x64. 3 LDS buffers (A 16KB + B 32KB each), 2-tile-deep prefetch,
// vmcnt(6) counted, 1 barrier per K-tile, 2 phases {8 ds_read || 3 stage -> lgkmcnt(0)
// -> 16 MFMA}. Chunk swizzle c ^= (row&7) on both stage-source and read (T2, rule 21).
// n-tile 0..4 -> Q (bias, SQ), 5..9 -> K, 10..14 -> V (bias, V^T packed store).
__global__ __launch_bounds__(512, 2) void gemm_qkv(const __bf16* __restrict__ A,
                                                   const __bf16* __restrict__ Bw,
                                                   const float* __restrict__ qbias,
                                                   const float* __restrict__ vbias,
                                                   __bf16* __restrict__ Qo,
                                                   __bf16* __restrict__ Ko,
                                                   __bf16* __restrict__ Vto,
                                                   float sq) {
  __shared__ __align__(16) __bf16 lds[3 * 24576];  // per buf: A[128][64] at 0, B[256][64] at 8192
  const int tid = threadIdx.x;
  const int lane = tid & 63, wave = tid >> 6;
  const int wrow = wave >> 2, wcol = wave & 3;
  const int r = lane & 15, g = lane >> 4;

  // 720 blocks = 8 XCD * (6 m-tiles * 15 n-tiles, n-major): X patch 1.97MB L2-resident
  const int orig = blockIdx.x;
  const int xcd = orig & 7, ii = orig >> 3;     // ii in [0,90)
  const int m_idx = xcd * 6 + ii % 6;           // [0,48)
  const int n_idx = ii / 6;                     // [0,15)
  const int m0 = m_idx * 128, n0 = n_idx * 256;

  const f32x4 fz = {0.f, 0.f, 0.f, 0.f};
  f32x4 acc[4][4];
#pragma unroll
  for (int mi = 0; mi < 4; ++mi)
#pragma unroll
    for (int ni = 0; ni < 4; ++ni) acc[mi][ni] = fz;

  // staging source pointers, chunk pre-swizzled: LDS(row,c) holds global chunk c^(row&7)
  const __bf16* srcA[2];
  const __bf16* srcB[4];
#pragma unroll
  for (int j = 0; j < 2; ++j) {
    const int slot = j * 512 + tid;
    const int row = slot >> 3, ch = slot & 7;
    srcA[j] = A + (size_t)(m0 + row) * 1280 + (ch ^ (row & 7)) * 8;
  }
#pragma unroll
  for (int j = 0; j < 4; ++j) {
    const int slot = j * 512 + tid;
    const int row = slot >> 3, ch = slot & 7;
    srcB[j] = Bw + (size_t)(n0 + row) * 1280 + (ch ^ (row & 7)) * 8;
  }
  const int wdst = wave * 512;  // dest elems: wave-uniform base, lane*16B appended by HW

  auto stage_h0 = [&](int buf, int kt2) {
    const int k0 = kt2 * 64;
    glds16(srcA[0] + k0, &lds[buf * 24576 + wdst]);
    glds16(srcA[1] + k0, &lds[buf * 24576 + 4096 + wdst]);
    glds16(srcB[0] + k0, &lds[buf * 24576 + 8192 + wdst]);
  };
  auto stage_h1 = [&](int buf, int kt2) {
    const int k0 = kt2 * 64;
    glds16(srcB[1] + k0, &lds[buf * 24576 + 12288 + wdst]);
    glds16(srcB[2] + k0, &lds[buf * 24576 + 16384 + wdst]);
    glds16(srcB[3] + k0, &lds[buf * 24576 + 20480 + wdst]);
  };

  // prologue: tiles 0 and 1 in flight; wait for tile 0 (oldest 6)
  stage_h0(0, 0); stage_h1(0, 0);
  stage_h0(1, 1); stage_h1(1, 1);
  asm volatile("s_waitcnt vmcnt(6)" ::: "memory");
  SB0();
  __builtin_amdgcn_s_barrier();
  SB0();

  const int aoff = (wrow * 64 + r) * 64;         // + mi*1024
  const int boff = 8192 + (wcol * 64 + r) * 64;  // + ni*1024
  const int c0 = (g ^ (r & 7)) * 8;              // ks=0 swizzled chunk
  const int c1 = ((4 + g) ^ (r & 7)) * 8;        // ks=1

  int cur = 0;
  for (int kt = 0; kt < 20; ++kt) {
    int nxt2 = cur + 2; if (nxt2 >= 3) nxt2 -= 3;
    const __bf16* Lb = &lds[cur * 24576];
    const bool pf = (kt + 2 < 20);

    // ---- phase 0 (ks=0): ds_read || stage half0 -> MFMA ----
    bf16x8 af[4], bfr[4];
#pragma unroll
    for (int mi = 0; mi < 4; ++mi) af[mi] = *(const bf16x8*)&Lb[aoff + mi * 1024 + c0];
#pragma unroll
    for (int ni = 0; ni < 4; ++ni) bfr[ni] = *(const bf16x8*)&Lb[boff + ni * 1024 + c0];
    if (pf) stage_h0(nxt2, kt + 2);
    asm volatile("s_waitcnt lgkmcnt(0)" ::: "memory");
    SB0();
    __builtin_amdgcn_s_setprio(1);
#pragma unroll
    for (int mi = 0; mi < 4; ++mi)
#pragma unroll
      for (int ni = 0; ni < 4; ++ni)
        acc[mi][ni] = mfma_bf16(af[mi], bfr[ni], acc[mi][ni]);
    __builtin_amdgcn_s_setprio(0);

    // ---- phase 1 (ks=1): ds_read || stage half1 -> MFMA ----
    bf16x8 af1[4], bfr1[4];
#pragma unroll
    for (int mi = 0; mi < 4; ++mi) af1[mi] = *(const bf16x8*)&Lb[aoff + mi * 1024 + c1];
#pragma unroll
    for (int ni = 0; ni < 4; ++ni) bfr1[ni] = *(const bf16x8*)&Lb[boff + ni * 1024 + c1];
    if (pf) stage_h1(nxt2, kt + 2);
    asm volatile("s_waitcnt lgkmcnt(0)" ::: "memory");
    SB0();
    __builtin_amdgcn_s_setprio(1);
#pragma unroll
    for (int mi = 0; mi < 4; ++mi)
#pragma unroll
      for (int ni = 0; ni < 4; ++ni)
        acc[mi][ni] = mfma_bf16(af1[mi], bfr1[ni], acc[mi][ni]);
    __builtin_amdgcn_s_setprio(0);

    // end of K-tile: next tile's loads (issued last iter) must have landed;
    // the 6 just-issued (tile kt+2) stay in flight across the barrier.
    if (pf) asm volatile("s_waitcnt vmcnt(6)" ::: "memory");
    else    asm volatile("s_waitcnt vmcnt(0)" ::: "memory");
    SB0();
    __builtin_amdgcn_s_barrier();
    SB0();
    cur = cur + 1; if (cur >= 3) cur -= 3;
  }

  const int which = n_idx / 5;                       // 0=Q 1=K 2=V (block-uniform)
  const int nb = n0 - which * 1280 + wcol * 64;      // panel-local col base
  const float scale = (which == 0) ? sq : 1.f;

#pragma unroll
  for (int ni = 0; ni < 4; ++ni) {
    const int col = nb + ni * 16 + r;
    const float bv = (which == 0) ? qbias[col] : (which == 2) ? vbias[col] : 0.f;
#pragma unroll
    for (int mi = 0; mi < 4; ++mi) {
      if (which == 2) {
        const int row0 = m0 + wrow * 64 + mi * 16 + g * 4;
        if (row0 < 6000) {
          const int bidx = row0 / 1500;              // 4-row group never straddles
          const int t = row0 - bidx * 1500;
          union { __bf16 h[4]; unsigned long long u; } pk;
#pragma unroll
          for (int rr = 0; rr < 4; ++rr) pk.h[rr] = (__bf16)(acc[mi][ni][rr] + bv);
          *(unsigned long long*)&Vto[((size_t)(bidx * 1280 + col)) * 1536 + t] = pk.u;
        }
      } else {
        __bf16* dst = (which == 0) ? Qo : Ko;
#pragma unroll
        for (int rr = 0; rr < 4; ++rr) {
          const int row = m0 + wrow * 64 + mi * 16 + g * 4 + rr;
          dst[(size_t)row * 1280 + col] = (__bf16)((acc[mi][ni][rr] + bv) * scale);
        }
      }
    }
  }
}

// ---------------- O-projection GEMM: A[6144][1280] @ W[1280][1280]^T -> f32 ----------
// r8 structure (proven): counted vmcnt(4) + SB0-fenced barriers + chunk swizzle.
__global__ __launch_bounds__(256) void gemm_o(const __bf16* __restrict__ A,
                                              const __bf16* __restrict__ Bw,
                                              const float* __restrict__ bias,
                                              float* __restrict__ out) {
  __shared__ __align__(16) __bf16 lds[2 * 8192];
  const int tid = threadIdx.x;
  const int lane = tid & 63, wave = tid >> 6;
  const int orig = blockIdx.x;
  const int xcd = orig & 7, i = orig >> 3;          // i in [0,60)
  const int m_idx = (xcd & 3) * 12 + i % 12;        // [0,48)
  const int n_idx = (xcd >> 2) * 5 + i / 12;        // [0,10)
  const int m0 = m_idx * 128, n0 = n_idx * 128;
  const int wm = (wave >> 1) * 64, wn = (wave & 1) * 64;
  const int r = lane & 15, g = lane >> 4;

  const f32x4 fz = {0.f, 0.f, 0.f, 0.f};
  f32x4 acc[4][4];
#pragma unroll
  for (int mi = 0; mi < 4; ++mi)
#pragma unroll
    for (int ni = 0; ni < 4; ++ni) acc[mi][ni] = fz;

  const int cg = 8 * ((tid & 3) ^ ((tid >> 3) & 3));
  const __bf16* Abase = A + (size_t)(m0 + (tid >> 2)) * 1280 + cg;
  const __bf16* Bbase = Bw + (size_t)(n0 + (tid >> 2)) * 1280 + cg;
  const int wA = wave * 512;
  const int csw = (g ^ ((lane >> 1) & 3)) * 8;

  auto stage = [&](int buf, int kt2) {
    const int k0 = kt2 * 32;
    __bf16* L = &lds[buf * 8192];
    glds16(Abase + k0, L + wA);
    glds16(Abase + 64 * 1280 + k0, L + wA + 2048);
    glds16(Bbase + k0, L + 4096 + wA);
    glds16(Bbase + 64 * 1280 + k0, L + 6144 + wA);
  };

  stage(0, 0);
  for (int kt = 0; kt < 40; ++kt) {
    const int cur = kt & 1;
    if (kt + 1 < 40) {
      stage(cur ^ 1, kt + 1);
      asm volatile("s_waitcnt vmcnt(4)" ::: "memory");
    } else {
      asm volatile("s_waitcnt vmcnt(0)" ::: "memory");
    }
    SB0();
    __builtin_amdgcn_s_barrier();
    SB0();

    const __bf16* Ab = &lds[cur * 8192];
    const __bf16* Bb = Ab + 4096;
    bf16x8 af[4], bfr[4];
#pragma unroll
    for (int mi = 0; mi < 4; ++mi)
      af[mi] = *(const bf16x8*)&Ab[(wm + mi * 16 + r) * 32 + csw];
#pragma unroll
    for (int ni = 0; ni < 4; ++ni)
      bfr[ni] = *(const bf16x8*)&Bb[(wn + ni * 16 + r) * 32 + csw];
#pragma unroll
    for (int mi = 0; mi < 4; ++mi)
#pragma unroll
      for (int ni = 0; ni < 4; ++ni)
        acc[mi][ni] = mfma_bf16(af[mi], bfr[ni], acc[mi][ni]);

    asm volatile("s_waitcnt lgkmcnt(0)" ::: "memory");
    SB0();
    __builtin_amdgcn_s_barrier();
    SB0();
  }

#pragma unroll
  for (int ni = 0; ni < 4; ++ni) {
    const int col = n0 + wn + ni * 16 + r;
    const float bv = bias[col];
#pragma unroll
    for (int mi = 0; mi < 4; ++mi) {
#pragma unroll
      for (int rr = 0; rr < 4; ++rr) {
        const int row = m0 + wm + mi * 16 + g * 4 + rr;
        if (row < 6000) out[(size_t)row * 1280 + col] = acc[mi][ni][rr] + bv;
      }
    }
  }
}

// ---------------- flash attention (swapped QK^T, fixed-max softmax, V^T input) -------
// Q pre-scaled by log2(e)/64, so P = exp2(S) directly. Unchanged from r7/r8 (passing).
__global__ __launch_bounds__(256) void flash_attn(const __bf16* __restrict__ Qg,
                                                  const __bf16* __restrict__ Kg,
                                                  const __bf16* __restrict__ Vt,
                                                  __bf16* __restrict__ Og) {
  constexpr int TQ = 1500, NKT = 24;
  __shared__ __align__(16) __bf16 lds[16384];

  const int tid = threadIdx.x;
  const int lane = tid & 63, w = tid >> 6;
  const int r = lane & 15, g = lane >> 4;

  const int orig = blockIdx.x;
  const int work = (orig & 7) * 120 + (orig >> 3);
  const int bh = work / 12, qb = work - bh * 12;
  const int b = bh / 20, h = bh - b * 20;
  const int q0 = qb * 128;
  const size_t base = (size_t)b * (TQ * 1280) + h * 64;
  const __bf16* Vt_bh = Vt + (size_t)(b * 1280 + h * 64) * 1536;

  const int k_src_col = 8 * ((lane & 7) ^ (lane >> 3));
  const int k_row_loc = w * 8 + (lane >> 3);
  const int v_d_loc = 8 * w + (lane >> 3);
  const int v_chunk = 8 * ((lane & 7) ^ (lane >> 3));

  bf16x8 qf[2][2];
#pragma unroll
  for (int qs = 0; qs < 2; ++qs) {
    int t = q0 + w * 32 + qs * 16 + r;
    t = t < TQ ? t : TQ - 1;
    const __bf16* qp = Qg + base + (size_t)t * 1280;
#pragma unroll
    for (int dk = 0; dk < 2; ++dk) qf[qs][dk] = *(const bf16x8*)(qp + dk * 32 + g * 8);
  }

  const f32x4 fz = {0.f, 0.f, 0.f, 0.f};
  f32x4 o_acc[2][4];
#pragma unroll
  for (int qs = 0; qs < 2; ++qs)
#pragma unroll
    for (int ni = 0; ni < 4; ++ni) o_acc[qs][ni] = fz;
  float l_run[2] = {0.f, 0.f};

  auto stage = [&](int buf, int kt2) {
    const int kb = kt2 * 64;
#pragma unroll
    for (int i = 0; i < 2; ++i) {
      int row = kb + i * 32 + k_row_loc;
      row = row < TQ ? row : TQ - 1;
      glds16(Kg + base + (size_t)row * 1280 + k_src_col,
             &lds[buf * 8192 + i * 2048 + w * 512]);
    }
#pragma unroll
    for (int i = 0; i < 2; ++i) {
      glds16(Vt_bh + (size_t)(32 * i + v_d_loc) * 1536 + kb + v_chunk,
             &lds[buf * 8192 + 4096 + i * 2048 + w * 512]);
    }
  };

  stage(0, 0);
  __syncthreads();
  for (int kt = 0; kt < NKT; ++kt) {
    const int cur = kt & 1;
    if (kt + 1 < NKT) stage(cur ^ 1, kt + 1);

    const __bf16* Kb = &lds[cur * 8192];

    f32x4 s[2][4];
#pragma unroll
    for (int qs = 0; qs < 2; ++qs)
#pragma unroll
      for (int nt = 0; nt < 4; ++nt) s[qs][nt] = fz;
#pragma unroll
    for (int dk = 0; dk < 2; ++dk) {
      bf16x8 kf[4];
#pragma unroll
      for (int nt = 0; nt < 4; ++nt) {
        const int row = nt * 16 + r;
        const int sc = (dk * 32 + g * 8) ^ ((r & 7) << 3);
        kf[nt] = *(const bf16x8*)&Kb[row * 64 + sc];
      }
#pragma unroll
      for (int qs = 0; qs < 2; ++qs)
#pragma unroll
        for (int nt = 0; nt < 4; ++nt) s[qs][nt] = mfma_bf16(kf[nt], qf[qs][dk], s[qs][nt]);
    }

    if (kt == NKT - 1) {
#pragma unroll
      for (int nt = 0; nt < 4; ++nt)
#pragma unroll
        for (int rr = 0; rr < 4; ++rr) {
          const int key = kt * 64 + nt * 16 + g * 4 + rr;
          if (key >= TQ) { s[0][nt][rr] = -1.0e30f; s[1][nt][rr] = -1.0e30f; }
        }
    }

#pragma unroll
    for (int qs = 0; qs < 2; ++qs) {
      float ssum = 0.f;
#pragma unroll
      for (int nt = 0; nt < 4; ++nt)
#pragma unroll
        for (int rr = 0; rr < 4; ++rr) {
          const float p = fast_exp2(s[qs][nt][rr]);
          s[qs][nt][rr] = p;
          ssum += p;
        }
      l_run[qs] += ssum;
    }

    const __bf16* Vbuf = &lds[cur * 8192 + 4096];
    const int swz = (r & 7) << 3;
#pragma unroll
    for (int ks = 0; ks < 2; ++ks) {
      bf16x8 pa[2];
#pragma unroll
      for (int qs = 0; qs < 2; ++qs) {
        bf16x8 t;
#pragma unroll
        for (int j = 0; j < 4; ++j) {
          t[j] = (__bf16)s[qs][2 * ks][j];
          t[4 + j] = (__bf16)s[qs][2 * ks + 1][j];
        }
        pa[qs] = t;
      }
      const int o1 = (32 * ks + 4 * g) ^ swz;
      const int o2 = (32 * ks + 16 + 4 * g) ^ swz;
#pragma unroll
      for (int ni = 0; ni < 4; ++ni) {
        const int dbase = (16 * ni + r) * 64;
        union { bf16x4 hh[2]; bf16x8 v; } u;
        u.hh[0] = *(const bf16x4*)&Vbuf[dbase + o1];
        u.hh[1] = *(const bf16x4*)&Vbuf[dbase + o2];
#pragma unroll
        for (int qs = 0; qs < 2; ++qs) o_acc[qs][ni] = mfma_bf16(u.v, pa[qs], o_acc[qs][ni]);
      }
    }

    __syncthreads();
  }

  float inv[2];
#pragma unroll
  for (int qs = 0; qs < 2; ++qs) {
    float l = l_run[qs];
    l += __shfl_xor(l, 16);
    l += __shfl_xor(l, 32);
    inv[qs] = 1.0f / l;
  }

  __bf16* Ob = &lds[w * 2304];
#pragma unroll
  for (int qs = 0; qs < 2; ++qs) {
#pragma unroll
    for (int ni = 0; ni < 4; ++ni)
#pragma unroll
      for (int rr = 0; rr < 4; ++rr)
        Ob[(qs * 16 + r) * 72 + ni * 16 + g * 4 + rr] = (__bf16)(o_acc[qs][ni][rr] * inv[qs]);
  }
  __syncthreads();
  const int qg = q0 + w * 32 + (lane >> 1);
  if (qg < TQ) {
#pragma unroll
    for (int v = 0; v < 4; ++v) {
      const int c = (lane & 1) * 32 + v * 8;
      bf16x8 val = *(const bf16x8*)&lds[w * 2304 + (lane >> 1) * 72 + c];
      *(bf16x8*)&Og[base + (size_t)qg * 1280 + c] = val;
    }
  }
}

// ---------------- launcher ----------------
extern "C" void kernel_launch(void* const* d_in, const int* in_sizes, int n_in,
                              void* d_out, int out_size, void* d_ws, size_t ws_size,
                              hipStream_t stream) {
  const float* hs = (const float*)d_in[0];
  const float* qw = (const float*)d_in[1];
  const float* qb = (const float*)d_in[2];
  const float* kw = (const float*)d_in[3];
  const float* vw = (const float*)d_in[4];
  const float* vb = (const float*)d_in[5];
  const float* ow = (const float*)d_in[6];
  const float* ob = (const float*)d_in[7];

  const long long MP = 6144LL * 1280;  // == 5120 * 1536 (Vt reuses this slot)
  const long long WE = 1280LL * 1280;
  __bf16* Xb = (__bf16*)d_ws;
  __bf16* Wq = Xb + MP;   // Wq/Wk/Wv contiguous -> single [3840][1280] B matrix
  __bf16* Wk = Wq + WE;
  __bf16* Wv = Wk + WE;
  __bf16* Wo = Wv + WE;
  __bf16* Qb = Wo + WE;
  __bf16* Kb = Qb + MP;
  __bf16* Vtb = Kb + MP;
  __bf16* Ab = Xb;  // alias: X dead after QKV projection

  cvt_bf16<<<3840, 256, 0, stream>>>(hs, Xb, 7680000);  // pads rows 6000..6143 with 0
  cvt_w4<<<3200, 256, 0, stream>>>(qw, kw, vw, ow, Wq, Wk, Wv, Wo);

  const float SQ = 1.4426950408889634f / 64.f;  // log2(e) / sqrt(64)^2
  gemm_qkv<<<720, 512, 0, stream>>>(Xb, Wq, qb, vb, Qb, Kb, Vtb, SQ);

  flash_attn<<<960, 256, 0, stream>>>(Qb, Kb, Vtb, Ab);

  gemm_o<<<480, 256, 0, stream>>>(Ab, Wo, ob, (float*)d_out);
}

// Round 10
// 175.684 us; speedup vs baseline: 1.1302x; 1.0254x over previous
//
#include <hip/hip_runtime.h>

typedef __attribute__((ext_vector_type(4))) float f32x4;
typedef __attribute__((ext_vector_type(8))) __bf16 bf16x8;
typedef __attribute__((ext_vector_type(4))) __bf16 bf16x4;

#define DEV __device__ __forceinline__

DEV f32x4 mfma_bf16(bf16x8 a, bf16x8 b, f32x4 c) {
  return __builtin_amdgcn_mfma_f32_16x16x32_bf16(a, b, c, 0, 0, 0);
}

DEV void glds16(const void* gp, void* lp) {
  __builtin_amdgcn_global_load_lds((const __attribute__((address_space(1))) void*)gp,
                                   (__attribute__((address_space(3))) void*)lp, 16, 0, 0);
}

DEV float fast_exp2(float x) {
#if __has_builtin(__builtin_amdgcn_exp2f)
  return __builtin_amdgcn_exp2f(x);
#else
  float r;
  asm("v_exp_f32 %0, %1" : "=v"(r) : "v"(x));
  return r;
#endif
}

#define SB0() __builtin_amdgcn_sched_barrier(0)

// ---------------- fused f32->bf16 conversions ----------------
// blocks 0..3839: hidden_states (zero-pad to 6144*1280); 3840..7039: the 4 weights.
__global__ __launch_bounds__(256) void cvt_all(const float* __restrict__ hs,
                                               const float* __restrict__ qw,
                                               const float* __restrict__ kw,
                                               const float* __restrict__ vw,
                                               const float* __restrict__ ow,
                                               __bf16* __restrict__ oX,
                                               __bf16* __restrict__ oQ,
                                               __bf16* __restrict__ oK,
                                               __bf16* __restrict__ oV,
                                               __bf16* __restrict__ oO) {
  const int blk = blockIdx.x;
  if (blk < 3840) {
    long long e = ((long long)blk * 256 + threadIdx.x) * 8;
    bf16x8 o = {};
    if (e < 7680000) {
      const f32x4* ip = (const f32x4*)(hs + e);
      f32x4 a = ip[0], b = ip[1];
#pragma unroll
      for (int j = 0; j < 4; ++j) { o[j] = (__bf16)a[j]; o[j + 4] = (__bf16)b[j]; }
    }
    *(bf16x8*)(oX + e) = o;
  } else {
    const int wb = blk - 3840;
    const int which = wb / 800;
    const int bb = wb - which * 800;
    const float* in = which == 0 ? qw : which == 1 ? kw : which == 2 ? vw : ow;
    __bf16* out = which == 0 ? oQ : which == 1 ? oK : which == 2 ? oV : oO;
    long long e = ((long long)bb * 256 + threadIdx.x) * 8;
    const f32x4* ip = (const f32x4*)(in + e);
    f32x4 x = ip[0], y = ip[1];
    bf16x8 o;
#pragma unroll
    for (int j = 0; j < 4; ++j) { o[j] = (__bf16)x[j]; o[j + 4] = (__bf16)y[j]; }
    *(bf16x8*)(out + e) = o;
  }
}

// ---------------- merged QKV GEMM, fine-interleaved counted schedule (r9, proven) ----
__global__ __launch_bounds__(512, 2) void gemm_qkv(const __bf16* __restrict__ A,
                                                   const __bf16* __restrict__ Bw,
                                                   const float* __restrict__ qbias,
                                                   const float* __restrict__ vbias,
                                                   __bf16* __restrict__ Qo,
                                                   __bf16* __restrict__ Ko,
                                                   __bf16* __restrict__ Vto,
                                                   float sq) {
  __shared__ __align__(16) __bf16 lds[3 * 24576];
  const int tid = threadIdx.x;
  const int lane = tid & 63, wave = tid >> 6;
  const int wrow = wave >> 2, wcol = wave & 3;
  const int r = lane & 15, g = lane >> 4;

  const int orig = blockIdx.x;
  const int xcd = orig & 7, ii = orig >> 3;     // ii in [0,90)
  const int m_idx = xcd * 6 + ii % 6;
  const int n_idx = ii / 6;
  const int m0 = m_idx * 128, n0 = n_idx * 256;

  const f32x4 fz = {0.f, 0.f, 0.f, 0.f};
  f32x4 acc[4][4];
#pragma unroll
  for (int mi = 0; mi < 4; ++mi)
#pragma unroll
    for (int ni = 0; ni < 4; ++ni) acc[mi][ni] = fz;

  const __bf16* srcA[2];
  const __bf16* srcB[4];
#pragma unroll
  for (int j = 0; j < 2; ++j) {
    const int slot = j * 512 + tid;
    const int row = slot >> 3, ch = slot & 7;
    srcA[j] = A + (size_t)(m0 + row) * 1280 + (ch ^ (row & 7)) * 8;
  }
#pragma unroll
  for (int j = 0; j < 4; ++j) {
    const int slot = j * 512 + tid;
    const int row = slot >> 3, ch = slot & 7;
    srcB[j] = Bw + (size_t)(n0 + row) * 1280 + (ch ^ (row & 7)) * 8;
  }
  const int wdst = wave * 512;

  auto stage_h0 = [&](int buf, int kt2) {
    const int k0 = kt2 * 64;
    glds16(srcA[0] + k0, &lds[buf * 24576 + wdst]);
    glds16(srcA[1] + k0, &lds[buf * 24576 + 4096 + wdst]);
    glds16(srcB[0] + k0, &lds[buf * 24576 + 8192 + wdst]);
  };
  auto stage_h1 = [&](int buf, int kt2) {
    const int k0 = kt2 * 64;
    glds16(srcB[1] + k0, &lds[buf * 24576 + 12288 + wdst]);
    glds16(srcB[2] + k0, &lds[buf * 24576 + 16384 + wdst]);
    glds16(srcB[3] + k0, &lds[buf * 24576 + 20480 + wdst]);
  };

  stage_h0(0, 0); stage_h1(0, 0);
  stage_h0(1, 1); stage_h1(1, 1);
  asm volatile("s_waitcnt vmcnt(6)" ::: "memory");
  SB0();
  __builtin_amdgcn_s_barrier();
  SB0();

  const int aoff = (wrow * 64 + r) * 64;
  const int boff = 8192 + (wcol * 64 + r) * 64;
  const int c0 = (g ^ (r & 7)) * 8;
  const int c1 = ((4 + g) ^ (r & 7)) * 8;

  int cur = 0;
  for (int kt = 0; kt < 20; ++kt) {
    int nxt2 = cur + 2; if (nxt2 >= 3) nxt2 -= 3;
    const __bf16* Lb = &lds[cur * 24576];
    const bool pf = (kt + 2 < 20);

    bf16x8 af[4], bfr[4];
#pragma unroll
    for (int mi = 0; mi < 4; ++mi) af[mi] = *(const bf16x8*)&Lb[aoff + mi * 1024 + c0];
#pragma unroll
    for (int ni = 0; ni < 4; ++ni) bfr[ni] = *(const bf16x8*)&Lb[boff + ni * 1024 + c0];
    if (pf) stage_h0(nxt2, kt + 2);
    asm volatile("s_waitcnt lgkmcnt(0)" ::: "memory");
    SB0();
    __builtin_amdgcn_s_setprio(1);
#pragma unroll
    for (int mi = 0; mi < 4; ++mi)
#pragma unroll
      for (int ni = 0; ni < 4; ++ni)
        acc[mi][ni] = mfma_bf16(af[mi], bfr[ni], acc[mi][ni]);
    __builtin_amdgcn_s_setprio(0);

    bf16x8 af1[4], bfr1[4];
#pragma unroll
    for (int mi = 0; mi < 4; ++mi) af1[mi] = *(const bf16x8*)&Lb[aoff + mi * 1024 + c1];
#pragma unroll
    for (int ni = 0; ni < 4; ++ni) bfr1[ni] = *(const bf16x8*)&Lb[boff + ni * 1024 + c1];
    if (pf) stage_h1(nxt2, kt + 2);
    asm volatile("s_waitcnt lgkmcnt(0)" ::: "memory");
    SB0();
    __builtin_amdgcn_s_setprio(1);
#pragma unroll
    for (int mi = 0; mi < 4; ++mi)
#pragma unroll
      for (int ni = 0; ni < 4; ++ni)
        acc[mi][ni] = mfma_bf16(af1[mi], bfr1[ni], acc[mi][ni]);
    __builtin_amdgcn_s_setprio(0);

    if (pf) asm volatile("s_waitcnt vmcnt(6)" ::: "memory");
    else    asm volatile("s_waitcnt vmcnt(0)" ::: "memory");
    SB0();
    __builtin_amdgcn_s_barrier();
    SB0();
    cur = cur + 1; if (cur >= 3) cur -= 3;
  }

  const int which = n_idx / 5;
  const int nb = n0 - which * 1280 + wcol * 64;
  const float scale = (which == 0) ? sq : 1.f;

#pragma unroll
  for (int ni = 0; ni < 4; ++ni) {
    const int col = nb + ni * 16 + r;
    const float bv = (which == 0) ? qbias[col] : (which == 2) ? vbias[col] : 0.f;
#pragma unroll
    for (int mi = 0; mi < 4; ++mi) {
      if (which == 2) {
        const int row0 = m0 + wrow * 64 + mi * 16 + g * 4;
        if (row0 < 6000) {
          const int bidx = row0 / 1500;
          const int t = row0 - bidx * 1500;
          union { __bf16 h[4]; unsigned long long u; } pk;
#pragma unroll
          for (int rr = 0; rr < 4; ++rr) pk.h[rr] = (__bf16)(acc[mi][ni][rr] + bv);
          *(unsigned long long*)&Vto[((size_t)(bidx * 1280 + col)) * 1536 + t] = pk.u;
        }
      } else {
        __bf16* dst = (which == 0) ? Qo : Ko;
#pragma unroll
        for (int rr = 0; rr < 4; ++rr) {
          const int row = m0 + wrow * 64 + mi * 16 + g * 4 + rr;
          dst[(size_t)row * 1280 + col] = (__bf16)((acc[mi][ni][rr] + bv) * scale);
        }
      }
    }
  }
}

// ---------------- O-projection GEMM, same fine-interleaved structure, f32 epilogue ----
__global__ __launch_bounds__(512, 2) void gemm_o(const __bf16* __restrict__ A,
                                                 const __bf16* __restrict__ Bw,
                                                 const float* __restrict__ bias,
                                                 float* __restrict__ out) {
  __shared__ __align__(16) __bf16 lds[3 * 24576];
  const int tid = threadIdx.x;
  const int lane = tid & 63, wave = tid >> 6;
  const int wrow = wave >> 2, wcol = wave & 3;
  const int r = lane & 15, g = lane >> 4;

  // 240 blocks = 8 XCD * (6 m-tiles * 5 n-tiles, n-major)
  const int orig = blockIdx.x;
  const int xcd = orig & 7, ii = orig >> 3;     // ii in [0,30)
  const int m_idx = xcd * 6 + ii % 6;
  const int n_idx = ii / 6;                     // [0,5)
  const int m0 = m_idx * 128, n0 = n_idx * 256;

  const f32x4 fz = {0.f, 0.f, 0.f, 0.f};
  f32x4 acc[4][4];
#pragma unroll
  for (int mi = 0; mi < 4; ++mi)
#pragma unroll
    for (int ni = 0; ni < 4; ++ni) acc[mi][ni] = fz;

  const __bf16* srcA[2];
  const __bf16* srcB[4];
#pragma unroll
  for (int j = 0; j < 2; ++j) {
    const int slot = j * 512 + tid;
    const int row = slot >> 3, ch = slot & 7;
    srcA[j] = A + (size_t)(m0 + row) * 1280 + (ch ^ (row & 7)) * 8;
  }
#pragma unroll
  for (int j = 0; j < 4; ++j) {
    const int slot = j * 512 + tid;
    const int row = slot >> 3, ch = slot & 7;
    srcB[j] = Bw + (size_t)(n0 + row) * 1280 + (ch ^ (row & 7)) * 8;
  }
  const int wdst = wave * 512;

  auto stage_h0 = [&](int buf, int kt2) {
    const int k0 = kt2 * 64;
    glds16(srcA[0] + k0, &lds[buf * 24576 + wdst]);
    glds16(srcA[1] + k0, &lds[buf * 24576 + 4096 + wdst]);
    glds16(srcB[0] + k0, &lds[buf * 24576 + 8192 + wdst]);
  };
  auto stage_h1 = [&](int buf, int kt2) {
    const int k0 = kt2 * 64;
    glds16(srcB[1] + k0, &lds[buf * 24576 + 12288 + wdst]);
    glds16(srcB[2] + k0, &lds[buf * 24576 + 16384 + wdst]);
    glds16(srcB[3] + k0, &lds[buf * 24576 + 20480 + wdst]);
  };

  stage_h0(0, 0); stage_h1(0, 0);
  stage_h0(1, 1); stage_h1(1, 1);
  asm volatile("s_waitcnt vmcnt(6)" ::: "memory");
  SB0();
  __builtin_amdgcn_s_barrier();
  SB0();

  const int aoff = (wrow * 64 + r) * 64;
  const int boff = 8192 + (wcol * 64 + r) * 64;
  const int c0 = (g ^ (r & 7)) * 8;
  const int c1 = ((4 + g) ^ (r & 7)) * 8;

  int cur = 0;
  for (int kt = 0; kt < 20; ++kt) {
    int nxt2 = cur + 2; if (nxt2 >= 3) nxt2 -= 3;
    const __bf16* Lb = &lds[cur * 24576];
    const bool pf = (kt + 2 < 20);

    bf16x8 af[4], bfr[4];
#pragma unroll
    for (int mi = 0; mi < 4; ++mi) af[mi] = *(const bf16x8*)&Lb[aoff + mi * 1024 + c0];
#pragma unroll
    for (int ni = 0; ni < 4; ++ni) bfr[ni] = *(const bf16x8*)&Lb[boff + ni * 1024 + c0];
    if (pf) stage_h0(nxt2, kt + 2);
    asm volatile("s_waitcnt lgkmcnt(0)" ::: "memory");
    SB0();
    __builtin_amdgcn_s_setprio(1);
#pragma unroll
    for (int mi = 0; mi < 4; ++mi)
#pragma unroll
      for (int ni = 0; ni < 4; ++ni)
        acc[mi][ni] = mfma_bf16(af[mi], bfr[ni], acc[mi][ni]);
    __builtin_amdgcn_s_setprio(0);

    bf16x8 af1[4], bfr1[4];
#pragma unroll
    for (int mi = 0; mi < 4; ++mi) af1[mi] = *(const bf16x8*)&Lb[aoff + mi * 1024 + c1];
#pragma unroll
    for (int ni = 0; ni < 4; ++ni) bfr1[ni] = *(const bf16x8*)&Lb[boff + ni * 1024 + c1];
    if (pf) stage_h1(nxt2, kt + 2);
    asm volatile("s_waitcnt lgkmcnt(0)" ::: "memory");
    SB0();
    __builtin_amdgcn_s_setprio(1);
#pragma unroll
    for (int mi = 0; mi < 4; ++mi)
#pragma unroll
      for (int ni = 0; ni < 4; ++ni)
        acc[mi][ni] = mfma_bf16(af1[mi], bfr1[ni], acc[mi][ni]);
    __builtin_amdgcn_s_setprio(0);

    if (pf) asm volatile("s_waitcnt vmcnt(6)" ::: "memory");
    else    asm volatile("s_waitcnt vmcnt(0)" ::: "memory");
    SB0();
    __builtin_amdgcn_s_barrier();
    SB0();
    cur = cur + 1; if (cur >= 3) cur -= 3;
  }

#pragma unroll
  for (int ni = 0; ni < 4; ++ni) {
    const int col = n0 + wcol * 64 + ni * 16 + r;
    const float bv = bias[col];
#pragma unroll
    for (int mi = 0; mi < 4; ++mi) {
#pragma unroll
      for (int rr = 0; rr < 4; ++rr) {
        const int row = m0 + wrow * 64 + mi * 16 + g * 4 + rr;
        if (row < 6000) out[(size_t)row * 1280 + col] = acc[mi][ni][rr] + bv;
      }
    }
  }
}

// ---------------- flash attention: counted-vmcnt pipeline (r8-proven protocol) -------
// Q pre-scaled by log2(e)/64, so P = exp2(S) directly. Compute body unchanged from r9.
__global__ __launch_bounds__(256) void flash_attn(const __bf16* __restrict__ Qg,
                                                  const __bf16* __restrict__ Kg,
                                                  const __bf16* __restrict__ Vt,
                                                  __bf16* __restrict__ Og) {
  constexpr int TQ = 1500, NKT = 24;
  __shared__ __align__(16) __bf16 lds[16384];

  const int tid = threadIdx.x;
  const int lane = tid & 63, w = tid >> 6;
  const int r = lane & 15, g = lane >> 4;

  const int orig = blockIdx.x;
  const int work = (orig & 7) * 120 + (orig >> 3);
  const int bh = work / 12, qb = work - bh * 12;
  const int b = bh / 20, h = bh - b * 20;
  const int q0 = qb * 128;
  const size_t base = (size_t)b * (TQ * 1280) + h * 64;
  const __bf16* Vt_bh = Vt + (size_t)(b * 1280 + h * 64) * 1536;

  const int k_src_col = 8 * ((lane & 7) ^ (lane >> 3));
  const int k_row_loc = w * 8 + (lane >> 3);
  const int v_d_loc = 8 * w + (lane >> 3);
  const int v_chunk = 8 * ((lane & 7) ^ (lane >> 3));

  bf16x8 qf[2][2];
#pragma unroll
  for (int qs = 0; qs < 2; ++qs) {
    int t = q0 + w * 32 + qs * 16 + r;
    t = t < TQ ? t : TQ - 1;
    const __bf16* qp = Qg + base + (size_t)t * 1280;
#pragma unroll
    for (int dk = 0; dk < 2; ++dk) qf[qs][dk] = *(const bf16x8*)(qp + dk * 32 + g * 8);
  }

  const f32x4 fz = {0.f, 0.f, 0.f, 0.f};
  f32x4 o_acc[2][4];
#pragma unroll
  for (int qs = 0; qs < 2; ++qs)
#pragma unroll
    for (int ni = 0; ni < 4; ++ni) o_acc[qs][ni] = fz;
  float l_run[2] = {0.f, 0.f};

  auto stage = [&](int buf, int kt2) {
    const int kb = kt2 * 64;
#pragma unroll
    for (int i = 0; i < 2; ++i) {
      int row = kb + i * 32 + k_row_loc;
      row = row < TQ ? row : TQ - 1;
      glds16(Kg + base + (size_t)row * 1280 + k_src_col,
             &lds[buf * 8192 + i * 2048 + w * 512]);
    }
#pragma unroll
    for (int i = 0; i < 2; ++i) {
      glds16(Vt_bh + (size_t)(32 * i + v_d_loc) * 1536 + kb + v_chunk,
             &lds[buf * 8192 + 4096 + i * 2048 + w * 512]);
    }
  };

  stage(0, 0);
  for (int kt = 0; kt < NKT; ++kt) {
    const int cur = kt & 1;
    if (kt + 1 < NKT) {
      stage(cur ^ 1, kt + 1);
      asm volatile("s_waitcnt vmcnt(4)" ::: "memory");  // cur landed; next in flight
    } else {
      asm volatile("s_waitcnt vmcnt(0)" ::: "memory");
    }
    SB0();
    __builtin_amdgcn_s_barrier();
    SB0();

    const __bf16* Kb = &lds[cur * 8192];

    // ---- S^T = K @ Q^T ----
    f32x4 s[2][4];
#pragma unroll
    for (int qs = 0; qs < 2; ++qs)
#pragma unroll
      for (int nt = 0; nt < 4; ++nt) s[qs][nt] = fz;
#pragma unroll
    for (int dk = 0; dk < 2; ++dk) {
      bf16x8 kf[4];
#pragma unroll
      for (int nt = 0; nt < 4; ++nt) {
        const int row = nt * 16 + r;
        const int sc = (dk * 32 + g * 8) ^ ((r & 7) << 3);
        kf[nt] = *(const bf16x8*)&Kb[row * 64 + sc];
      }
#pragma unroll
      for (int qs = 0; qs < 2; ++qs)
#pragma unroll
        for (int nt = 0; nt < 4; ++nt) s[qs][nt] = mfma_bf16(kf[nt], qf[qs][dk], s[qs][nt]);
    }

    // ---- mask invalid keys (last tile only) ----
    if (kt == NKT - 1) {
#pragma unroll
      for (int nt = 0; nt < 4; ++nt)
#pragma unroll
        for (int rr = 0; rr < 4; ++rr) {
          const int key = kt * 64 + nt * 16 + g * 4 + rr;
          if (key >= TQ) { s[0][nt][rr] = -1.0e30f; s[1][nt][rr] = -1.0e30f; }
        }
    }

    // ---- fixed-max softmax ----
#pragma unroll
    for (int qs = 0; qs < 2; ++qs) {
      float ssum = 0.f;
#pragma unroll
      for (int nt = 0; nt < 4; ++nt)
#pragma unroll
        for (int rr = 0; rr < 4; ++rr) {
          const float p = fast_exp2(s[qs][nt][rr]);
          s[qs][nt][rr] = p;
          ssum += p;
        }
      l_run[qs] += ssum;
    }

    // ---- O^T += V^T @ P^T ----
    const __bf16* Vbuf = &lds[cur * 8192 + 4096];
    const int swz = (r & 7) << 3;
#pragma unroll
    for (int ks = 0; ks < 2; ++ks) {
      bf16x8 pa[2];
#pragma unroll
      for (int qs = 0; qs < 2; ++qs) {
        bf16x8 t;
#pragma unroll
        for (int j = 0; j < 4; ++j) {
          t[j] = (__bf16)s[qs][2 * ks][j];
          t[4 + j] = (__bf16)s[qs][2 * ks + 1][j];
        }
        pa[qs] = t;
      }
      const int o1 = (32 * ks + 4 * g) ^ swz;
      const int o2 = (32 * ks + 16 + 4 * g) ^ swz;
#pragma unroll
      for (int ni = 0; ni < 4; ++ni) {
        const int dbase = (16 * ni + r) * 64;
        union { bf16x4 hh[2]; bf16x8 v; } u;
        u.hh[0] = *(const bf16x4*)&Vbuf[dbase + o1];
        u.hh[1] = *(const bf16x4*)&Vbuf[dbase + o2];
#pragma unroll
        for (int qs = 0; qs < 2; ++qs) o_acc[qs][ni] = mfma_bf16(u.v, pa[qs], o_acc[qs][ni]);
      }
    }

    asm volatile("s_waitcnt lgkmcnt(0)" ::: "memory");  // my ds_reads of buf[cur] retired
    SB0();
    __builtin_amdgcn_s_barrier();
    SB0();
  }

  // ---- final denominator reduce + normalize + store ----
  float inv[2];
#pragma unroll
  for (int qs = 0; qs < 2; ++qs) {
    float l = l_run[qs];
    l += __shfl_xor(l, 16);
    l += __shfl_xor(l, 32);
    inv[qs] = 1.0f / l;
  }

  __bf16* Ob = &lds[w * 2304];
#pragma unroll
  for (int qs = 0; qs < 2; ++qs) {
#pragma unroll
    for (int ni = 0; ni < 4; ++ni)
#pragma unroll
      for (int rr = 0; rr < 4; ++rr)
        Ob[(qs * 16 + r) * 72 + ni * 16 + g * 4 + rr] = (__bf16)(o_acc[qs][ni][rr] * inv[qs]);
  }
  __syncthreads();
  const int qg = q0 + w * 32 + (lane >> 1);
  if (qg < TQ) {
#pragma unroll
    for (int v = 0; v < 4; ++v) {
      const int c = (lane & 1) * 32 + v * 8;
      bf16x8 val = *(const bf16x8*)&lds[w * 2304 + (lane >> 1) * 72 + c];
      *(bf16x8*)&Og[base + (size_t)qg * 1280 + c] = val;
    }
  }
}

// ---------------- launcher ----------------
extern "C" void kernel_launch(void* const* d_in, const int* in_sizes, int n_in,
                              void* d_out, int out_size, void* d_ws, size_t ws_size,
                              hipStream_t stream) {
  const float* hs = (const float*)d_in[0];
  const float* qw = (const float*)d_in[1];
  const float* qb = (const float*)d_in[2];
  const float* kw = (const float*)d_in[3];
  const float* vw = (const float*)d_in[4];
  const float* vb = (const float*)d_in[5];
  const float* ow = (const float*)d_in[6];
  const float* ob = (const float*)d_in[7];

  const long long MP = 6144LL * 1280;  // == 5120 * 1536 (Vt reuses this slot)
  const long long WE = 1280LL * 1280;
  __bf16* Xb = (__bf16*)d_ws;
  __bf16* Wq = Xb + MP;   // Wq/Wk/Wv contiguous -> single [3840][1280] B matrix
  __bf16* Wk = Wq + WE;
  __bf16* Wv = Wk + WE;
  __bf16* Wo = Wv + WE;
  __bf16* Qb = Wo + WE;
  __bf16* Kb = Qb + MP;
  __bf16* Vtb = Kb + MP;
  __bf16* Ab = Xb;  // alias: X dead after QKV projection

  cvt_all<<<7040, 256, 0, stream>>>(hs, qw, kw, vw, ow, Xb, Wq, Wk, Wv, Wo);

  const float SQ = 1.4426950408889634f / 64.f;  // log2(e) / sqrt(64)^2
  gemm_qkv<<<720, 512, 0, stream>>>(Xb, Wq, qb, vb, Qb, Kb, Vtb, SQ);

  flash_attn<<<960, 256, 0, stream>>>(Qb, Kb, Vtb, Ab);

  gemm_o<<<240, 512, 0, stream>>>(Ab, Wo, ob, (float*)d_out);
}